// Round 1
// 91.540 us; speedup vs baseline: 1.0169x; 1.0169x over previous
//
#include <hip/hip_runtime.h>
#include <math.h>

#define B_ 4
#define T_ 512
#define D_ 128
#define H_ 64
#define DEMO_ 12
#define LOG2E 1.4426950408889634f
#define SC2   (2.0f * LOG2E)          // fold tanh's 2x and the exp2 conversion

typedef float float4v __attribute__((ext_vector_type(4)));
typedef float float2v __attribute__((ext_vector_type(2)));

// ---- kernel 1: Q' = (input@Wt)*SC2 [B*T,H]; K2T' = ((input@Wx)+demo@Wd+bh)*SC2 [B,H,T]
// 512 blocks x 512 threads (was 256x256 = 1 block/CU): each block owns 4 rows,
// each (row,h) dot is split across 2 threads (D halves) -> 16 waves/CU.
// K2T stores transposed through LDS -> one dwordx4 per (h) instead of 4 scattered dwords.
__global__ __launch_bounds__(512) void prep_kernel(
    const float* __restrict__ input, const float* __restrict__ demo,
    const float* __restrict__ Wt, const float* __restrict__ Wx,
    const float* __restrict__ Wd, const float* __restrict__ bh,
    const float* __restrict__ Wa, const float* __restrict__ ba,
    float* __restrict__ Q, float* __restrict__ K2T, float* __restrict__ Cs)
{
    __shared__ float in_sh[4 * D_];          // 4 rows x 128
    __shared__ float acc_sh[2][4][2][H_];    // [half][row][q/x][h]
    __shared__ float k2_sh[4][H_];           // [row][h] staging for transposed store

    int tid  = threadIdx.x;
    int row0 = blockIdx.x * 4;               // global row in [0, B*T)
    int b    = row0 >> 9;                    // T_ == 512, 4-row group never crosses batch

    in_sh[tid] = input[(size_t)row0 * D_ + tid];   // 512 floats, 1 per thread
    __syncthreads();

    int h    = tid & 63;
    int s    = tid >> 6;                     // 0..7
    int r    = s & 3;                        // row within block
    int half = s >> 2;                       // D-half

    const float* ish = &in_sh[r * D_ + half * 64];
    const float* wt  = Wt + (size_t)(half * 64) * H_ + h;
    const float* wx  = Wx + (size_t)(half * 64) * H_ + h;
    float q = 0.f, x = 0.f;
    #pragma unroll 8
    for (int k = 0; k < 64; ++k) {
        float a = ish[k];                    // LDS broadcast (uniform per wave)
        q = fmaf(a, wt[(size_t)k * H_], q);  // coalesced 256B, L2-hot
        x = fmaf(a, wx[(size_t)k * H_], x);
    }
    acc_sh[half][r][0][h] = q;
    acc_sh[half][r][1][h] = x;
    __syncthreads();

    if (tid < 256) {
        int h2 = tid & 63, r2 = tid >> 6;
        float dB = bh[h2];
        #pragma unroll
        for (int k = 0; k < DEMO_; ++k)
            dB = fmaf(demo[b * DEMO_ + k], Wd[k * H_ + h2], dB);
        float qv = (acc_sh[0][r2][0][h2] + acc_sh[1][r2][0][h2]) * SC2;
        float xv = (acc_sh[0][r2][1][h2] + acc_sh[1][r2][1][h2] + dB) * SC2;
        Q[(size_t)(row0 + r2) * H_ + h2] = qv;       // coalesced
        k2_sh[r2][h2] = xv;
    }
    __syncthreads();

    if (tid < 64) {                          // transposed K2T store: 16B per h
        float4v v = { k2_sh[0][tid], k2_sh[1][tid], k2_sh[2][tid], k2_sh[3][tid] };
        int t0 = row0 & (T_ - 1);
        *(float4v*)&K2T[((size_t)(b * H_ + tid)) * T_ + t0] = v;
    }

    if (blockIdx.x == 0 && tid < 64) {
        float w = Wa[tid];
        #pragma unroll
        for (int off = 32; off; off >>= 1) w += __shfl_down(w, off, 64);
        if (tid == 0) Cs[0] = (ba[0] + w) * LOG2E;
    }
}

// ---- kernel 2: causal scores + softmax + v, UNIFORM-WORK blocks -------------
// grid (128, B); 512 threads = 8 waves. Block y owns rows {2y,2y+1} (A) and
// {510-2y,511-2y} (B): total causal work = 1026 row-cols for EVERY block.
// Rowmax phase REMOVED: subtracting any per-row constant cancels in
// p/(s+1e-7) (scores are tanh-bounded, |eg| <~ 10 in log2 -> no overflow;
// epsilon perturbation <= 2^max*1e-7 ~ 1e-6, far under tolerance).
// K2T loads explicitly double-buffered (kc/kn ping-pong).
__global__ __launch_bounds__(512, 4) void attn_kernel(
    const float* __restrict__ input,
    const float* __restrict__ Qs, const float* __restrict__ K2T,
    const float* __restrict__ Wa, const float* __restrict__ Cs,
    float* __restrict__ out_v, float* __restrict__ out_e)
{
    __shared__ float   qsh[H_ * 4];       // [h][r]
    __shared__ float   p_sh[T_ * 4];      // [j][r]  (unnormalized, masked)
    __shared__ float4v red_s[8];          // [wave]
    __shared__ float   partial[16][4 * D_]; // [s][r*128+d]

    int tid  = threadIdx.x;
    int y    = blockIdx.x;                // [0,128)
    int b    = blockIdx.y;
    int lane = tid & 63, wv = tid >> 6;
    int j    = tid;
    int iA0  = 2 * y,       iA1 = iA0 + 1;
    int iB0  = 510 - 2 * y, iB1 = iB0 + 1;

    if (tid < 256) {                      // qsh[h*4+r] = Q'[i_r, h]
        int h  = tid >> 2, r = tid & 3;
        int ir = (r < 2) ? (iA0 + r) : (iB0 + r - 2);
        qsh[tid] = Qs[(size_t)(b * T_ + ir) * H_ + h];
    }
    __syncthreads();                      // B0

    const float* k2p = K2T + (size_t)b * H_ * T_ + j;
    float CL   = Cs[0];
    bool  actA = (wv << 6) <= iA1;        // actA implies actB (iA1 < iB1)
    bool  actB = (wv << 6) <= iB1;

    float aA0 = 0.f, aA1 = 0.f, aB0 = 0.f, aB1 = 0.f;
    if (actA) {                           // 4-row h-loop
        float kc[8], kn[8];
        #pragma unroll
        for (int u = 0; u < 8; ++u) kc[u] = k2p[(size_t)u * T_];
        #pragma unroll 1
        for (int h0 = 0; h0 < H_; h0 += 8) {
            if (h0 + 8 < H_) {
                #pragma unroll
                for (int u = 0; u < 8; ++u) kn[u] = k2p[(size_t)(h0 + 8 + u) * T_];
            }
            #pragma unroll
            for (int u = 0; u < 8; ++u) {
                float wa   = Wa[h0 + u];                        // s_load
                float4v q4 = *(const float4v*)&qsh[(h0 + u) * 4];
                float e0 = __builtin_amdgcn_exp2f(q4[0] + kc[u]);
                float e1 = __builtin_amdgcn_exp2f(q4[1] + kc[u]);
                float e2 = __builtin_amdgcn_exp2f(q4[2] + kc[u]);
                float e3 = __builtin_amdgcn_exp2f(q4[3] + kc[u]);
                aA0 = fmaf(wa, __builtin_amdgcn_rcpf(1.0f + e0), aA0);
                aA1 = fmaf(wa, __builtin_amdgcn_rcpf(1.0f + e1), aA1);
                aB0 = fmaf(wa, __builtin_amdgcn_rcpf(1.0f + e2), aB0);
                aB1 = fmaf(wa, __builtin_amdgcn_rcpf(1.0f + e3), aB1);
            }
            if (h0 + 8 < H_) {
                #pragma unroll
                for (int u = 0; u < 8; ++u) kc[u] = kn[u];
            }
        }
    } else if (actB) {                    // 2-row h-loop (B rows only)
        float kc[8], kn[8];
        #pragma unroll
        for (int u = 0; u < 8; ++u) kc[u] = k2p[(size_t)u * T_];
        #pragma unroll 1
        for (int h0 = 0; h0 < H_; h0 += 8) {
            if (h0 + 8 < H_) {
                #pragma unroll
                for (int u = 0; u < 8; ++u) kn[u] = k2p[(size_t)(h0 + 8 + u) * T_];
            }
            #pragma unroll
            for (int u = 0; u < 8; ++u) {
                float wa   = Wa[h0 + u];
                float2v q2 = *(const float2v*)&qsh[(h0 + u) * 4 + 2];
                float e2 = __builtin_amdgcn_exp2f(q2[0] + kc[u]);
                float e3 = __builtin_amdgcn_exp2f(q2[1] + kc[u]);
                aB0 = fmaf(wa, __builtin_amdgcn_rcpf(1.0f + e2), aB0);
                aB1 = fmaf(wa, __builtin_amdgcn_rcpf(1.0f + e3), aB1);
            }
            if (h0 + 8 < H_) {
                #pragma unroll
                for (int u = 0; u < 8; ++u) kc[u] = kn[u];
            }
        }
    }

    // p directly (no rowmax): eg is log2 of the score's exp; bounded by tanh.
    float p0 = (j <= iA0) ? __builtin_amdgcn_exp2f(fmaf(-SC2, aA0, CL)) : 0.0f;
    float p1 = (j <= iA1) ? __builtin_amdgcn_exp2f(fmaf(-SC2, aA1, CL)) : 0.0f;
    float p2 = (j <= iB0) ? __builtin_amdgcn_exp2f(fmaf(-SC2, aB0, CL)) : 0.0f;
    float p3 = (j <= iB1) ? __builtin_amdgcn_exp2f(fmaf(-SC2, aB1, CL)) : 0.0f;
    *(float4v*)&p_sh[j * 4] = (float4v){p0, p1, p2, p3};

    float S0 = p0, S1 = p1, S2 = p2, S3 = p3;
    #pragma unroll
    for (int off = 32; off; off >>= 1) {
        S0 += __shfl_down(S0, off, 64);
        S1 += __shfl_down(S1, off, 64);
        S2 += __shfl_down(S2, off, 64);
        S3 += __shfl_down(S3, off, 64);
    }
    if (lane == 0) red_s[wv] = (float4v){S0, S1, S2, S3};
    __syncthreads();                      // B1 (covers red_s and p_sh)

    float inv0, inv1, inv2, inv3;
    {
        float4v s = red_s[0];
        #pragma unroll
        for (int w = 1; w < 8; ++w) {
            float4v sw = red_s[w];
            s[0] += sw[0]; s[1] += sw[1]; s[2] += sw[2]; s[3] += sw[3];
        }
        inv0 = __builtin_amdgcn_rcpf(s[0] + 1e-7f);
        inv1 = __builtin_amdgcn_rcpf(s[1] + 1e-7f);
        inv2 = __builtin_amdgcn_rcpf(s[2] + 1e-7f);
        inv3 = __builtin_amdgcn_rcpf(s[3] + 1e-7f);
    }

    // v-phase: thread = (s-chunk of 32 j, d4 of 4 d). dwordx4 input loads,
    // b128 broadcast p reads, 16 fma per j. p==0 past each row's diagonal.
    {
        int s  = tid >> 5, d4 = tid & 31;
        float4v va0 = {0,0,0,0}, va1 = {0,0,0,0}, va2 = {0,0,0,0}, va3 = {0,0,0,0};
        if ((s << 5) <= iB1) {            // chunk has at least one unmasked j
            const float* inp = input + ((size_t)(b * T_) + (s << 5)) * D_ + (d4 << 2);
            const float* pp  = p_sh + (s << 5) * 4;
            #pragma unroll 4
            for (int jj = 0; jj < 32; ++jj) {
                float4v x  = *(const float4v*)(inp + (size_t)jj * D_);
                float4v p4 = *(const float4v*)(pp + jj * 4);
                va0 += x * p4[0];
                va1 += x * p4[1];
                va2 += x * p4[2];
                va3 += x * p4[3];
            }
        }
        *(float4v*)&partial[s][0 * D_ + (d4 << 2)] = va0;
        *(float4v*)&partial[s][1 * D_ + (d4 << 2)] = va1;
        *(float4v*)&partial[s][2 * D_ + (d4 << 2)] = va2;
        *(float4v*)&partial[s][3 * D_ + (d4 << 2)] = va3;
    }
    __syncthreads();                      // B2

    {
        int r  = tid >> 7, d = tid & 127;
        float v = 0.f;
        #pragma unroll
        for (int ss = 0; ss < 16; ++ss) v += partial[ss][r * D_ + d];
        int   ir  = (r < 2) ? (iA0 + r) : (iB0 + r - 2);
        float inv = (r == 0) ? inv0 : (r == 1) ? inv1 : (r == 2) ? inv2 : inv3;
        out_v[(size_t)(b * T_ + ir) * D_ + d] = v * inv;
    }

    // e-writes last: no barrier after, stores drain at kernel end
    out_e[((size_t)(b * T_ + iA0)) * T_ + j] = p0 * inv0;
    out_e[((size_t)(b * T_ + iA1)) * T_ + j] = p1 * inv1;
    out_e[((size_t)(b * T_ + iB0)) * T_ + j] = p2 * inv2;
    out_e[((size_t)(b * T_ + iB1)) * T_ + j] = p3 * inv3;
}

extern "C" void kernel_launch(void* const* d_in, const int* in_sizes, int n_in,
                              void* d_out, int out_size, void* d_ws, size_t ws_size,
                              hipStream_t stream)
{
    const float* input = (const float*)d_in[0];
    const float* demo  = (const float*)d_in[1];
    const float* Wt    = (const float*)d_in[2];
    const float* Wx    = (const float*)d_in[3];
    const float* Wd    = (const float*)d_in[4];
    const float* bh    = (const float*)d_in[5];
    const float* Wa    = (const float*)d_in[6];
    const float* ba    = (const float*)d_in[7];

    float* out_v = (float*)d_out;                     // [B,T,D]
    float* out_e = out_v + (size_t)B_ * T_ * D_;      // [B,T,T]

    float* Q   = (float*)d_ws;                        // [B*T, H]  (pre-scaled)
    float* K2T = Q + (size_t)B_ * T_ * H_;            // [B, H, T] (pre-scaled)
    float* Cs  = K2T + (size_t)B_ * H_ * T_;          // [1]

    prep_kernel<<<dim3(B_ * T_ / 4), 512, 0, stream>>>(input, demo, Wt, Wx, Wd, bh,
                                                       Wa, ba, Q, K2T, Cs);
    attn_kernel<<<dim3(128, B_), 512, 0, stream>>>(input, Q, K2T, Wa, Cs, out_v, out_e);
}